// Round 19
// baseline (199.818 us; speedup 1.0000x reference)
//
#include <hip/hip_runtime.h>
#include <hip/hip_bf16.h>

typedef unsigned short u16;
typedef unsigned long long u64;
typedef __attribute__((ext_vector_type(4))) float f32x4;
typedef __attribute__((ext_vector_type(8))) short bf16x8;

#define NE 3072
#define DM 128
#define NH 8
#define HD 16
#define NL 3
#define NR 64
#define FF 512
#define CUT 10.0f
#define CAP 96
#define GRID 96
#define BR 32
#define THREADS 1024
#define NCLS 256

#define PK_QKV_A 0
#define PK_WO_A  49152
#define PK_QKV_E 65536
#define PK_WO_E  114688
#define PK_W1    131072
#define PK_W2    196608
#define PK_WRBF  262144
#define PK_LAYER 270336

__device__ __forceinline__ short f2b(float f) {
    union { __hip_bfloat16 b; short s; } u;
    u.b = __float2bfloat16(f);
    return u.s;
}
__device__ __forceinline__ void ast64(u64* p, u64 v) {
    __hip_atomic_store(p, v, __ATOMIC_RELAXED, __HIP_MEMORY_SCOPE_AGENT);
}
__device__ __forceinline__ void astf(float* p, float v) {
    __hip_atomic_store(p, v, __ATOMIC_RELAXED, __HIP_MEMORY_SCOPE_AGENT);
}
__device__ __forceinline__ float bfx(u64 v, int i) {
    return __uint_as_float(((unsigned)(v >> (16 * i)) & 0xFFFFu) << 16);
}

// 16x16 MFMA tile: A bf16 from LDS base (stride S shorts), B packed bf16
template <int KT, int S>
__device__ __forceinline__ f32x4 tileAb(const short* As, const short* Bt, int l) {
    f32x4 acc = {0.f, 0.f, 0.f, 0.f};
#pragma unroll
    for (int kt = 0; kt < KT; kt++) {
        bf16x8 av = *(const bf16x8*)(As + (l & 15) * S + kt * 32 + 8 * (l >> 4));
        bf16x8 bv = *(const bf16x8*)(Bt + kt * 512 + l * 8);
        acc = __builtin_amdgcn_mfma_f32_16x16x32_bf16(av, bv, acc, 0, 0, 0);
    }
    return acc;
}

// grid barrier: release-add, relaxed poll
__device__ __forceinline__ void gbar(int* cnt, int target) {
    __syncthreads();
    if (threadIdx.x == 0) {
        __hip_atomic_fetch_add(cnt, 1, __ATOMIC_RELEASE, __HIP_MEMORY_SCOPE_AGENT);
        while (__hip_atomic_load(cnt, __ATOMIC_RELAXED, __HIP_MEMORY_SCOPE_AGENT) < target)
            __builtin_amdgcn_s_sleep(2);
        asm volatile("" ::: "memory");
    }
    __syncthreads();
}

// ---------------- weight pack ----------------
struct WSrc { const float* W[11]; };

__global__ __launch_bounds__(256)
void pack_w(WSrc ws, short* __restrict__ dst) {
    int gid = blockIdx.x * 256 + threadIdx.x;
    if (gid >= NL * PK_LAYER) return;
    int layer = gid / PK_LAYER, e = gid % PK_LAYER;
    int kind, off, K, N;
    if (e < 49152)       { kind = e / 16384;            off = e % 16384;      K = 128; N = 128; }
    else if (e < 65536)  { kind = 3;                    off = e - 49152;      K = 128; N = 128; }
    else if (e < 114688) { kind = 4 + (e - 65536) / 16384; off = (e - 65536) % 16384; K = 128; N = 128; }
    else if (e < 131072) { kind = 7;                    off = e - 114688;     K = 128; N = 128; }
    else if (e < 196608) { kind = 8;                    off = e - 131072;     K = 128; N = 512; }
    else if (e < 262144) { kind = 9;                    off = e - 196608;     K = 512; N = 128; }
    else                 { kind = 10;                   off = e - 262144;     K = 64;  N = 128; }
    int i = off & 7, lane = (off >> 3) & 63, ft = off >> 9;
    int KT = K >> 5;
    int kt = ft % KT, nt = ft / KT;
    int n = nt * 16 + (lane & 15);
    int k = kt * 32 + 8 * (lane >> 4) + i;
    const float* W = ws.W[kind] + (size_t)layer * K * N;
    dst[gid] = f2b(W[k * N + n]);
}

// ---------------- sort machinery ----------------
__global__ void zero_hist(int* hist, int* barcnt) {
    hist[threadIdx.x] = 0;
    if (threadIdx.x == 0) *barcnt = 0;
}

__global__ __launch_bounds__(256)
void k_meta(const int* __restrict__ eidx, const int* __restrict__ bids,
            int4* __restrict__ meta, int* __restrict__ key, int* __restrict__ hist) {
    int e = blockIdx.x * 256 + threadIdx.x;
    if (e >= NE) return;
    int s = eidx[e], d = eidx[NE + e];
    int bs = bids[s], bd = bids[d];
    meta[e] = make_int4(s, d, bs, bd);
    int kk = bs * 16 + bd;
    key[e] = kk;
    atomicAdd(&hist[kk], 1);
}

__global__ __launch_bounds__(256)
void k_scan(const int* __restrict__ hist, int* __restrict__ cls_start,
            int* __restrict__ fill) {
    __shared__ int sh[NCLS];
    int t = threadIdx.x;
    sh[t] = hist[t];
    __syncthreads();
    for (int off = 1; off < NCLS; off <<= 1) {
        int v = (t >= off) ? sh[t - off] : 0;
        __syncthreads();
        sh[t] += v;
        __syncthreads();
    }
    cls_start[t + 1] = sh[t];
    if (t == 0) cls_start[0] = 0;
    fill[t] = sh[t] - hist[t];
}

__global__ __launch_bounds__(256)
void k_scatter(const int* __restrict__ key, int* __restrict__ fill,
               int* __restrict__ perm) {
    int e = blockIdx.x * 256 + threadIdx.x;
    if (e >= NE) return;
    int pos = atomicAdd(&fill[key[e]], 1);
    perm[pos] = e;
}

// ---------------- prep in permuted order ----------------
__global__ __launch_bounds__(64)
void prep2(const float* __restrict__ ef, const float* __restrict__ ec,
           const float* __restrict__ nc, const int* __restrict__ perm,
           const int4* __restrict__ metaO, int4* __restrict__ meta2,
           float* __restrict__ h, float* __restrict__ xv, float* __restrict__ rbf) {
    int p = blockIdx.x, lane = threadIdx.x;
    int e = perm[p];
    int4 me = metaO[e];
    if (lane == 0) meta2[p] = me;
    h[p * DM + lane]      = ef[e * DM + lane];
    h[p * DM + 64 + lane] = ef[e * DM + 64 + lane];
    if (lane < 4) xv[p * 4 + lane] = (lane < 3) ? ec[e * 3 + lane] : 0.f;
    float dx = nc[me.y * 3 + 0] - nc[me.x * 3 + 0];
    float dy = nc[me.y * 3 + 1] - nc[me.x * 3 + 1];
    float dz = nc[me.y * 3 + 2] - nc[me.x * 3 + 2];
    float dist = sqrtf(dx * dx + dy * dy + dz * dz);
    float t = fminf(fmaxf(dist / CUT, 0.f), 1.f);
    float fc = 0.5f * (cosf(3.14159265358979f * t) + 1.f);
    float width = CUT / NR;
    float center = (CUT * lane) / (NR - 1);
    float u = (dist - center) / width;
    rbf[p * NR + lane] = expf(-u * u) * fc;
}

// ---------------- inter neighbor lists ----------------
__global__ __launch_bounds__(64)
void build_lists(const int4* __restrict__ meta2,
                 u16* __restrict__ idx_e, int* __restrict__ cnt_e) {
    __shared__ int ce;
    __shared__ u16 be[CAP];
    int i = blockIdx.x, lane = threadIdx.x;
    if (lane == 0) ce = 0;
    __syncthreads();
    int4 mi = meta2[i];
    for (int j = lane; j < NE; j += 64) {
        int4 mj = meta2[j];
        bool intra_b = (mi.z == mj.z) && (mi.w == mj.w);
        bool share = (mi.x == mj.x) || (mi.x == mj.y) ||
                     (mi.y == mj.x) || (mi.y == mj.y);
        bool oke = (share && !intra_b) || (i == j);
        if (oke) { int p = atomicAdd(&ce, 1); if (p < CAP) be[p] = (u16)j; }
    }
    __syncthreads();
    int ne_ = min(ce, CAP);
    if (lane == 0) cnt_e[i] = ne_;
    for (int p = lane; p < ne_; p += 64) idx_e[i * CAP + p] = be[p];
}

// ---------------- intra attention: class-range neighbors, prefetched cached loads ----------------
// unit = tid>>2 (256 units = 32 rows x 8 heads), sub = tid&3
__device__ __forceinline__ void attn_intra(
    const short (&qsb)[BR][136], const u64* __restrict__ kvaL,
    const float* __restrict__ xr, const int4* __restrict__ meta2,
    const int* __restrict__ cls_start,
    short (&ob)[BR][136], float (&pxs)[NH][BR][3],
    int m0, int tid)
{
    int unit = tid >> 2, sub = tid & 3;
    int rowl = unit >> 3, head = unit & 7, row = m0 + rowl;
    const u64* q64 = reinterpret_cast<const u64*>(&qsb[rowl][head * HD]);
    u64 qc[4];
#pragma unroll
    for (int t = 0; t < 4; t++) qc[t] = q64[t];
    int4 mr = meta2[row];
    int c = mr.z * 16 + mr.w;
    int nb0 = cls_start[c], nb1 = cls_start[c + 1];

    float m = -1e30f, li = 0.f;
    float acc[HD + 3];
#pragma unroll
    for (int d = 0; d < HD + 3; d++) acc[d] = 0.f;

    int p2 = nb0 + sub;
    bool have = p2 < nb1;
    int pc = have ? p2 : nb0;
    const u64* kb = kvaL + ((size_t)head * NE + pc) * 8;
    u64 kc[4], vc[4];
#pragma unroll
    for (int t = 0; t < 4; t++) { kc[t] = kb[t]; vc[t] = kb[4 + t]; }
    float x0 = xr[pc * 4], x1 = xr[pc * 4 + 1], x2 = xr[pc * 4 + 2];

    while (have) {
        int pn = p2 + 4;
        bool haveN = pn < nb1;
        int pl = haveN ? pn : nb0;
        const u64* kbn = kvaL + ((size_t)head * NE + pl) * 8;
        u64 nk[4], nv[4];
#pragma unroll
        for (int t = 0; t < 4; t++) { nk[t] = kbn[t]; nv[t] = kbn[4 + t]; }
        float nx0 = xr[pl * 4], nx1 = xr[pl * 4 + 1], nx2 = xr[pl * 4 + 2];

        float s = 0.f;
#pragma unroll
        for (int t = 0; t < 4; t++)
#pragma unroll
            for (int i = 0; i < 4; i++) s += bfx(qc[t], i) * bfx(kc[t], i);
        s *= 0.25f;
        if (s > m) {
            float cr = __expf(m - s);
            m = s; li *= cr;
#pragma unroll
            for (int d = 0; d < HD + 3; d++) acc[d] *= cr;
        }
        float pw = __expf(s - m);
        li += pw;
#pragma unroll
        for (int t = 0; t < 4; t++)
#pragma unroll
            for (int i = 0; i < 4; i++) acc[t * 4 + i] += pw * bfx(vc[t], i);
        acc[HD] += pw * x0; acc[HD + 1] += pw * x1; acc[HD + 2] += pw * x2;

        p2 = pn; have = haveN;
#pragma unroll
        for (int t = 0; t < 4; t++) { kc[t] = nk[t]; vc[t] = nv[t]; }
        x0 = nx0; x1 = nx1; x2 = nx2;
    }

    float mA = fmaxf(m, __shfl_xor(m, 1));
    mA = fmaxf(mA, __shfl_xor(mA, 2));
    float cf = __expf(m - mA);
    li *= cf;
#pragma unroll
    for (int d = 0; d < HD + 3; d++) acc[d] *= cf;
#pragma unroll
    for (int off = 1; off <= 2; off <<= 1) {
        li += __shfl_xor(li, off);
#pragma unroll
        for (int d = 0; d < HD + 3; d++) acc[d] += __shfl_xor(acc[d], off);
    }
    if (sub == 0) {
        float inv = 1.f / li;
#pragma unroll
        for (int d = 0; d < HD; d += 2) {
            unsigned loq = (u16)f2b(acc[d] * inv);
            unsigned hiq = (u16)f2b(acc[d + 1] * inv);
            *reinterpret_cast<unsigned*>(&ob[rowl][head * HD + d]) = loq | (hiq << 16);
        }
        pxs[head][rowl][0] = acc[HD] * inv;
        pxs[head][rowl][1] = acc[HD + 1] * inv;
        pxs[head][rowl][2] = acc[HD + 2] * inv;
    }
}

// ---------------- inter attention: prefetched cached gathers ----------------
__device__ __forceinline__ void attn_inter(
    const short (&qsb)[BR][136], const u64* __restrict__ kveL,
    const u16* __restrict__ idx, const int* __restrict__ cnt,
    short (&ob)[BR][136], int m0, int tid)
{
    int unit = tid >> 2, sub = tid & 3;
    int rowl = unit >> 3, head = unit & 7, row = m0 + rowl;
    const u64* q64 = reinterpret_cast<const u64*>(&qsb[rowl][head * HD]);
    u64 qc[4];
#pragma unroll
    for (int t = 0; t < 4; t++) qc[t] = q64[t];
    const u64* kvh = kveL + (size_t)head * NE * 8;
    int n = cnt[row];
    float m = -1e30f, li = 0.f;
    float acc[HD];
#pragma unroll
    for (int d = 0; d < HD; d++) acc[d] = 0.f;

    int p = sub;
    bool have = p < n;
    int jc = have ? (int)idx[row * CAP + p] : 0;
    const u64* kb = kvh + (size_t)jc * 8;
    u64 kc[4], vc[4];
#pragma unroll
    for (int t = 0; t < 4; t++) { kc[t] = kb[t]; vc[t] = kb[4 + t]; }

    while (have) {
        int pn = p + 4;
        bool haveN = pn < n;
        int jn = haveN ? (int)idx[row * CAP + pn] : 0;
        const u64* kbn = kvh + (size_t)jn * 8;
        u64 nk[4], nv[4];
#pragma unroll
        for (int t = 0; t < 4; t++) { nk[t] = kbn[t]; nv[t] = kbn[4 + t]; }

        float s = 0.f;
#pragma unroll
        for (int t = 0; t < 4; t++)
#pragma unroll
            for (int i = 0; i < 4; i++) s += bfx(qc[t], i) * bfx(kc[t], i);
        s *= 0.25f;
        if (s > m) {
            float cr = __expf(m - s);
            m = s; li *= cr;
#pragma unroll
            for (int d = 0; d < HD; d++) acc[d] *= cr;
        }
        float pw = __expf(s - m);
        li += pw;
#pragma unroll
        for (int t = 0; t < 4; t++)
#pragma unroll
            for (int i = 0; i < 4; i++) acc[t * 4 + i] += pw * bfx(vc[t], i);

        p = pn; have = haveN;
#pragma unroll
        for (int t = 0; t < 4; t++) { kc[t] = nk[t]; vc[t] = nv[t]; }
    }

    float mA = fmaxf(m, __shfl_xor(m, 1));
    mA = fmaxf(mA, __shfl_xor(mA, 2));
    float cf = __expf(m - mA);
    li *= cf;
#pragma unroll
    for (int d = 0; d < HD; d++) acc[d] *= cf;
#pragma unroll
    for (int off = 1; off <= 2; off <<= 1) {
        li += __shfl_xor(li, off);
#pragma unroll
        for (int d = 0; d < HD; d++) acc[d] += __shfl_xor(acc[d], off);
    }
    if (sub == 0) {
        float inv = 1.f / li;
#pragma unroll
        for (int d = 0; d < HD; d += 2) {
            unsigned loq = (u16)f2b(acc[d] * inv);
            unsigned hiq = (u16)f2b(acc[d + 1] * inv);
            *reinterpret_cast<unsigned*>(&ob[rowl][head * HD + d]) = loq | (hiq << 16);
        }
    }
}

// LN over row pair (wave w: rows 2w, 2w+1; 16 waves cover 32 rows)
__device__ __forceinline__ void ln_rows(float (&zs)[BR][132], float (&hF)[BR][132],
                                        short* hB, const float* g, const float* b,
                                        int w, int l) {
#pragma unroll
    for (int rr = 0; rr < 2; rr++) {
        int r = 2 * w + rr;
        float z0 = zs[r][l], z1 = zs[r][64 + l];
        float s = z0 + z1;
#pragma unroll
        for (int off = 32; off; off >>= 1) s += __shfl_xor(s, off);
        float mean = s * (1.f / DM);
        float d0 = z0 - mean, d1 = z1 - mean;
        float vs = d0 * d0 + d1 * d1;
#pragma unroll
        for (int off = 32; off; off >>= 1) vs += __shfl_xor(vs, off);
        float inv = rsqrtf(vs * (1.f / DM) + 1e-5f);
        float h0 = d0 * inv * g[l] + b[l];
        float h1 = d1 * inv * g[64 + l] + b[64 + l];
        hF[r][l] = h0; hF[r][64 + l] = h1;
        hB[r * 136 + l] = f2b(h0);
        hB[r * 136 + 64 + l] = f2b(h1);
    }
}

// ---------------- persistent mega kernel (32 rows/block, 96 blocks, 16 waves) ----------------
__global__ __launch_bounds__(THREADS)
void mega_kernel(const float* __restrict__ h_init, const float* __restrict__ rbf_g,
                 const int4* __restrict__ meta2, const int* __restrict__ cls_start,
                 const int* __restrict__ perm,
                 const u16* __restrict__ idx_e, const int* __restrict__ cnt_e,
                 const short* __restrict__ pk,
                 const float* __restrict__ b1g, const float* __restrict__ b2g,
                 const float* __restrict__ ln1g, const float* __restrict__ ln1b,
                 const float* __restrict__ ln2g, const float* __restrict__ ln2b,
                 const float* __restrict__ ln3g, const float* __restrict__ ln3b,
                 const float* __restrict__ Wcg, const float* __restrict__ bcg,
                 short* __restrict__ kva, short* __restrict__ kve,
                 float* __restrict__ xv, int* __restrict__ barcnt,
                 float* __restrict__ outp)
{
    __shared__ float hL[BR][132];
    __shared__ float hn[BR][132];
    __shared__ float zs[BR][132];
    __shared__ short qsb[BR][136];
    __shared__ short hb[BR][136];
    __shared__ short hnb[BR][136];
    __shared__ short ob[BR][136];
    __shared__ short rbfb[BR][72];
    __shared__ short ub[BR][520];
    __shared__ float pxs[NH][BR][3];

    int tid = threadIdx.x, w = tid >> 6, l = tid & 63;
    int m0 = blockIdx.x * BR;
    int R4 = 4 * (l >> 4), c0 = l & 15;
    int rt = w >> 3, ct = w & 7;        // row-tile, col-tile for 32x128 outputs
    int rb = rt * 16;                    // row base

    for (int i = tid; i < BR * 128; i += THREADS) hL[i >> 7][i & 127] = h_init[m0 * DM + i];
    for (int i = tid; i < BR * 64; i += THREADS) rbfb[i >> 6][i & 63] = f2b(rbf_g[m0 * NR + i]);
    __syncthreads();

    int ph = 0;
    for (int lay = 0; lay < NL; lay++) {
        const short* Lb = pk + (size_t)lay * PK_LAYER;
        const float* xr = xv + (size_t)lay * NE * 4;
        float* xw2 = xv + (size_t)(lay + 1) * NE * 4;
        u64* kvaL = reinterpret_cast<u64*>(kva) + (size_t)lay * NH * NE * 8;
        u64* kveL = reinterpret_cast<u64*>(kve) + (size_t)lay * NH * NE * 8;
        bool last = (lay == NL - 1);

        // P1a: hn = hL + rbf@Wrbf  (16 tiles: wave (rt,ct))
        {
            f32x4 acc = tileAb<2, 72>(&rbfb[rb][0], Lb + PK_WRBF + ct * 1024, l);
#pragma unroll
            for (int r = 0; r < 4; r++) {
                float z = acc[r] + hL[rb + R4 + r][ct * 16 + c0];
                hn[rb + R4 + r][ct * 16 + c0] = z;
                hnb[rb + R4 + r][ct * 16 + c0] = f2b(z);
            }
        }
        __syncthreads();
        // P1b: q->LDS(bf16); fused k|v -> kvaL (write-through)
        {
            f32x4 aq = tileAb<4, 136>(&hnb[rb][0], Lb + PK_QKV_A + 0 * 16384 + ct * 2048, l);
#pragma unroll
            for (int r = 0; r < 4; r++) qsb[rb + R4 + r][ct * 16 + c0] = f2b(aq[r]);
            f32x4 ak = tileAb<4, 136>(&hnb[rb][0], Lb + PK_QKV_A + 1 * 16384 + ct * 2048, l);
            f32x4 av = tileAb<4, 136>(&hnb[rb][0], Lb + PK_QKV_A + 2 * 16384 + ct * 2048, l);
#pragma unroll
            for (int r = 0; r < 4; r++) {
                ub[rb + R4 + r][ct * 16 + c0] = f2b(ak[r]);
                ub[rb + R4 + r][128 + ct * 16 + c0] = f2b(av[r]);
            }
            __syncthreads();
            for (int u = tid; u < BR * 64; u += THREADS) {
                int r = u >> 6, rest = u & 63, hh = rest >> 3, j = rest & 7;
                int so = (j < 4) ? (hh * 16 + j * 4) : (128 + hh * 16 + (j - 4) * 4);
                u64 val = *reinterpret_cast<const u64*>(&ub[r][so]);
                ast64(kvaL + ((size_t)hh * NE + m0 + r) * 8 + j, val);
            }
        }
        gbar(barcnt, GRID * (++ph));

        // P2: intra attn + Wo + LN1
        attn_intra(qsb, kvaL, xr, meta2, cls_start, ob, pxs, m0, tid);
        __syncthreads();
        {
            f32x4 d = tileAb<4, 136>(&ob[rb][0], Lb + PK_WO_A + ct * 2048, l);
#pragma unroll
            for (int r = 0; r < 4; r++)
                zs[rb + R4 + r][ct * 16 + c0] = d[r] + hn[rb + R4 + r][ct * 16 + c0];
        }
        __syncthreads();
        ln_rows(zs, hL, &hb[0][0], ln1g + lay * DM, ln1b + lay * DM, w, l);
        __syncthreads();

        // P3: qkv_e -> kveL
        {
            f32x4 aq = tileAb<4, 136>(&hb[rb][0], Lb + PK_QKV_E + 0 * 16384 + ct * 2048, l);
#pragma unroll
            for (int r = 0; r < 4; r++) qsb[rb + R4 + r][ct * 16 + c0] = f2b(aq[r]);
            f32x4 ak = tileAb<4, 136>(&hb[rb][0], Lb + PK_QKV_E + 1 * 16384 + ct * 2048, l);
            f32x4 av = tileAb<4, 136>(&hb[rb][0], Lb + PK_QKV_E + 2 * 16384 + ct * 2048, l);
#pragma unroll
            for (int r = 0; r < 4; r++) {
                ub[rb + R4 + r][ct * 16 + c0] = f2b(ak[r]);
                ub[rb + R4 + r][128 + ct * 16 + c0] = f2b(av[r]);
            }
            __syncthreads();
            for (int u = tid; u < BR * 64; u += THREADS) {
                int r = u >> 6, rest = u & 63, hh = rest >> 3, j = rest & 7;
                int so = (j < 4) ? (hh * 16 + j * 4) : (128 + hh * 16 + (j - 4) * 4);
                u64 val = *reinterpret_cast<const u64*>(&ub[r][so]);
                ast64(kveL + ((size_t)hh * NE + m0 + r) * 8 + j, val);
            }
        }
        gbar(barcnt, GRID * (++ph));

        // P4: inter attn + Wo + LN2
        attn_inter(qsb, kveL, idx_e, cnt_e, ob, m0, tid);
        __syncthreads();
        {
            f32x4 d = tileAb<4, 136>(&ob[rb][0], Lb + PK_WO_E + ct * 2048, l);
#pragma unroll
            for (int r = 0; r < 4; r++)
                zs[rb + R4 + r][ct * 16 + c0] = d[r] + hL[rb + R4 + r][ct * 16 + c0];
        }
        __syncthreads();
        ln_rows(zs, hL, &hb[0][0], ln2g + lay * DM, ln2b + lay * DM, w, l);
        __syncthreads();

        // P5: FFN1 -> ub  (64 tiles: t = w*4+j, rtt=t>>5, ctt=t&31)
#pragma unroll
        for (int j = 0; j < 4; j++) {
            int t = w * 4 + j;
            int rtt = t >> 5, ctt = t & 31;
            f32x4 acc = tileAb<4, 136>(&hb[rtt * 16][0], Lb + PK_W1 + ctt * 2048, l);
#pragma unroll
            for (int r = 0; r < 4; r++) {
                int col = ctt * 16 + c0;
                float xvv = acc[r] + b1g[lay * FF + col];
                xvv = xvv / (1.f + __expf(-xvv));
                ub[rtt * 16 + R4 + r][col] = f2b(xvv);
            }
        }
        __syncthreads();
        // FFN2 -> zs  (16 tiles: wave (rt,ct), K=512)
        {
            f32x4 acc = tileAb<16, 520>(&ub[rb][0], Lb + PK_W2 + ct * 8192, l);
#pragma unroll
            for (int r = 0; r < 4; r++)
                zs[rb + R4 + r][ct * 16 + c0] = acc[r] + b2g[lay * DM + ct * 16 + c0]
                                              + hL[rb + R4 + r][ct * 16 + c0];
        }
        __syncthreads();
        // LN3 + gate + coord (wave w: rows 2w, 2w+1)
        {
            const float* g3 = ln3g + lay * DM;
            const float* b3 = ln3b + lay * DM;
            const float* Wcl = Wcg + lay * DM;
            float bc0 = bcg[lay];
#pragma unroll
            for (int rr = 0; rr < 2; rr++) {
                int r = 2 * w + rr, row = m0 + r;
                int orow = perm[row];
                float z0 = zs[r][l], z1 = zs[r][64 + l];
                float s = z0 + z1;
#pragma unroll
                for (int off = 32; off; off >>= 1) s += __shfl_xor(s, off);
                float mean = s * (1.f / DM);
                float d0 = z0 - mean, d1 = z1 - mean;
                float vsum = d0 * d0 + d1 * d1;
#pragma unroll
                for (int off = 32; off; off >>= 1) vsum += __shfl_xor(vsum, off);
                float inv = rsqrtf(vsum * (1.f / DM) + 1e-5f);
                float h0 = d0 * inv * g3[l] + b3[l];
                float h1 = d1 * inv * g3[64 + l] + b3[64 + l];
                hL[r][l] = h0; hL[r][64 + l] = h1;
                if (last) { outp[orow * DM + l] = h0; outp[orow * DM + 64 + l] = h1; }
                float dc = h0 * Wcl[l] + h1 * Wcl[64 + l];
#pragma unroll
                for (int off = 32; off; off >>= 1) dc += __shfl_xor(dc, off);
                float gate = tanhf(dc + bc0);
                if (l < 3) {
                    float pxm = 0.f;
#pragma unroll
                    for (int hh = 0; hh < NH; hh++) pxm += pxs[hh][r][l];
                    pxm *= 0.125f;
                    float xvv = xr[row * 4 + l];
                    float nx = xvv + gate * (xvv - pxm);
                    astf(xw2 + row * 4 + l, nx);
                    if (last) outp[NE * DM + orow * 3 + l] = nx;
                }
            }
        }
        __syncthreads();
    }
}

extern "C" void kernel_launch(void* const* d_in, const int* in_sizes, int n_in,
                              void* d_out, int out_size, void* d_ws, size_t ws_size,
                              hipStream_t stream) {
    const float* ef   = (const float*)d_in[0];
    const float* ec   = (const float*)d_in[1];
    const int*   eidx = (const int*)d_in[2];
    const float* nc   = (const float*)d_in[3];
    const int*   bids = (const int*)d_in[4];
    const float* b1   = (const float*)d_in[14];
    const float* b2   = (const float*)d_in[16];
    const float* ln1g = (const float*)d_in[17];
    const float* ln1b = (const float*)d_in[18];
    const float* ln2g = (const float*)d_in[19];
    const float* ln2b = (const float*)d_in[20];
    const float* ln3g = (const float*)d_in[21];
    const float* ln3b = (const float*)d_in[22];
    const float* Wc   = (const float*)d_in[24];
    const float* bc   = (const float*)d_in[25];
    float* out = (float*)d_out;

    char* w = (char*)d_ws;
    auto carve = [&](size_t bytes) { char* p = w; w += ((bytes + 255) / 256) * 256; return p; };
    int*   barcnt = (int*)carve(256);
    int*   hist   = (int*)carve(NCLS * 4);
    int*   csta   = (int*)carve((NCLS + 1) * 4);
    int*   fill   = (int*)carve(NCLS * 4);
    int*   key    = (int*)carve((size_t)NE * 4);
    int*   perm   = (int*)carve((size_t)NE * 4);
    int4*  metaO  = (int4*)carve((size_t)NE * 16);
    int4*  meta2  = (int4*)carve((size_t)NE * 16);
    float* xv     = (float*)carve((size_t)(NL + 1) * NE * 4 * 4);
    int*   cnt_e  = (int*)carve((size_t)NE * 4);
    u16*   idx_e  = (u16*)carve((size_t)NE * CAP * 2);
    float* rbf_g  = (float*)carve((size_t)NE * NR * 4);
    float* h_in   = (float*)carve((size_t)NE * DM * 4);
    short* kva    = (short*)carve((size_t)NL * NH * NE * 32 * 2);
    short* kve    = (short*)carve((size_t)NL * NH * NE * 32 * 2);
    short* pk     = (short*)carve((size_t)NL * PK_LAYER * 2);

    WSrc ws;
    ws.W[0] = (const float*)d_in[5];   ws.W[1] = (const float*)d_in[6];
    ws.W[2] = (const float*)d_in[7];   ws.W[3] = (const float*)d_in[8];
    ws.W[4] = (const float*)d_in[9];   ws.W[5] = (const float*)d_in[10];
    ws.W[6] = (const float*)d_in[11];  ws.W[7] = (const float*)d_in[12];
    ws.W[8] = (const float*)d_in[13];  ws.W[9] = (const float*)d_in[15];
    ws.W[10] = (const float*)d_in[23];
    pack_w<<<(NL * PK_LAYER + 255) / 256, 256, 0, stream>>>(ws, pk);

    zero_hist<<<1, 256, 0, stream>>>(hist, barcnt);
    k_meta<<<(NE + 255) / 256, 256, 0, stream>>>(eidx, bids, metaO, key, hist);
    k_scan<<<1, 256, 0, stream>>>(hist, csta, fill);
    k_scatter<<<(NE + 255) / 256, 256, 0, stream>>>(key, fill, perm);
    prep2<<<NE, 64, 0, stream>>>(ef, ec, nc, perm, metaO, meta2, h_in, xv, rbf_g);
    build_lists<<<NE, 64, 0, stream>>>(meta2, idx_e, cnt_e);

    mega_kernel<<<GRID, THREADS, 0, stream>>>(h_in, rbf_g, meta2, csta, perm,
                                              idx_e, cnt_e, pk,
                                              b1, b2, ln1g, ln1b, ln2g, ln2b, ln3g, ln3b,
                                              Wc, bc, kva, kve, xv, barcnt, out);
}

// Round 20
// 198.860 us; speedup vs baseline: 1.0048x; 1.0048x over previous
//
#include <hip/hip_runtime.h>
#include <hip/hip_bf16.h>

typedef unsigned short u16;
typedef unsigned long long u64;
typedef __attribute__((ext_vector_type(4))) float f32x4;
typedef __attribute__((ext_vector_type(8))) short bf16x8;

#define NE 3072
#define DM 128
#define NH 8
#define HD 16
#define NL 3
#define NR 64
#define FF 512
#define CUT 10.0f
#define CAP 96
#define GRID 96
#define BR 32
#define THREADS 1024
#define NCLS 256

#define PK_QKV_A 0
#define PK_WO_A  49152
#define PK_QKV_E 65536
#define PK_WO_E  114688
#define PK_W1    131072
#define PK_W2    196608
#define PK_WRBF  262144
#define PK_LAYER 270336

__device__ __forceinline__ short f2b(float f) {
    union { __hip_bfloat16 b; short s; } u;
    u.b = __float2bfloat16(f);
    return u.s;
}
__device__ __forceinline__ void ast64(u64* p, u64 v) {
    __hip_atomic_store(p, v, __ATOMIC_RELAXED, __HIP_MEMORY_SCOPE_AGENT);
}
__device__ __forceinline__ void astf(float* p, float v) {
    __hip_atomic_store(p, v, __ATOMIC_RELAXED, __HIP_MEMORY_SCOPE_AGENT);
}
__device__ __forceinline__ float bfx(u64 v, int i) {
    return __uint_as_float(((unsigned)(v >> (16 * i)) & 0xFFFFu) << 16);
}

// 16x16 MFMA tile: A bf16 from LDS base (stride S shorts), B packed bf16
template <int KT, int S>
__device__ __forceinline__ f32x4 tileAb(const short* As, const short* Bt, int l) {
    f32x4 acc = {0.f, 0.f, 0.f, 0.f};
#pragma unroll
    for (int kt = 0; kt < KT; kt++) {
        bf16x8 av = *(const bf16x8*)(As + (l & 15) * S + kt * 32 + 8 * (l >> 4));
        bf16x8 bv = *(const bf16x8*)(Bt + kt * 512 + l * 8);
        acc = __builtin_amdgcn_mfma_f32_16x16x32_bf16(av, bv, acc, 0, 0, 0);
    }
    return acc;
}

// grid barrier: release-add, relaxed poll
__device__ __forceinline__ void gbar(int* cnt, int target) {
    __syncthreads();
    if (threadIdx.x == 0) {
        __hip_atomic_fetch_add(cnt, 1, __ATOMIC_RELEASE, __HIP_MEMORY_SCOPE_AGENT);
        while (__hip_atomic_load(cnt, __ATOMIC_RELAXED, __HIP_MEMORY_SCOPE_AGENT) < target)
            __builtin_amdgcn_s_sleep(2);
        asm volatile("" ::: "memory");
    }
    __syncthreads();
}

// ---------------- weight pack ----------------
struct WSrc { const float* W[11]; };

__global__ __launch_bounds__(256)
void pack_w(WSrc ws, short* __restrict__ dst) {
    int gid = blockIdx.x * 256 + threadIdx.x;
    if (gid >= NL * PK_LAYER) return;
    int layer = gid / PK_LAYER, e = gid % PK_LAYER;
    int kind, off, K, N;
    if (e < 49152)       { kind = e / 16384;            off = e % 16384;      K = 128; N = 128; }
    else if (e < 65536)  { kind = 3;                    off = e - 49152;      K = 128; N = 128; }
    else if (e < 114688) { kind = 4 + (e - 65536) / 16384; off = (e - 65536) % 16384; K = 128; N = 128; }
    else if (e < 131072) { kind = 7;                    off = e - 114688;     K = 128; N = 128; }
    else if (e < 196608) { kind = 8;                    off = e - 131072;     K = 128; N = 512; }
    else if (e < 262144) { kind = 9;                    off = e - 196608;     K = 512; N = 128; }
    else                 { kind = 10;                   off = e - 262144;     K = 64;  N = 128; }
    int i = off & 7, lane = (off >> 3) & 63, ft = off >> 9;
    int KT = K >> 5;
    int kt = ft % KT, nt = ft / KT;
    int n = nt * 16 + (lane & 15);
    int k = kt * 32 + 8 * (lane >> 4) + i;
    const float* W = ws.W[kind] + (size_t)layer * K * N;
    dst[gid] = f2b(W[k * N + n]);
}

// ---------------- sort machinery ----------------
__global__ void zero_hist(int* hist, int* barcnt) {
    hist[threadIdx.x] = 0;
    if (threadIdx.x == 0) *barcnt = 0;
}

__global__ __launch_bounds__(256)
void k_meta(const int* __restrict__ eidx, const int* __restrict__ bids,
            int4* __restrict__ meta, int* __restrict__ key, int* __restrict__ hist) {
    int e = blockIdx.x * 256 + threadIdx.x;
    if (e >= NE) return;
    int s = eidx[e], d = eidx[NE + e];
    int bs = bids[s], bd = bids[d];
    meta[e] = make_int4(s, d, bs, bd);
    int kk = bs * 16 + bd;
    key[e] = kk;
    atomicAdd(&hist[kk], 1);
}

__global__ __launch_bounds__(256)
void k_scan(const int* __restrict__ hist, int* __restrict__ cls_start,
            int* __restrict__ fill) {
    __shared__ int sh[NCLS];
    int t = threadIdx.x;
    sh[t] = hist[t];
    __syncthreads();
    for (int off = 1; off < NCLS; off <<= 1) {
        int v = (t >= off) ? sh[t - off] : 0;
        __syncthreads();
        sh[t] += v;
        __syncthreads();
    }
    cls_start[t + 1] = sh[t];
    if (t == 0) cls_start[0] = 0;
    fill[t] = sh[t] - hist[t];
}

__global__ __launch_bounds__(256)
void k_scatter(const int* __restrict__ key, int* __restrict__ fill,
               int* __restrict__ perm) {
    int e = blockIdx.x * 256 + threadIdx.x;
    if (e >= NE) return;
    int pos = atomicAdd(&fill[key[e]], 1);
    perm[pos] = e;
}

// ---------------- prep in permuted order ----------------
__global__ __launch_bounds__(64)
void prep2(const float* __restrict__ ef, const float* __restrict__ ec,
           const float* __restrict__ nc, const int* __restrict__ perm,
           const int4* __restrict__ metaO, int4* __restrict__ meta2,
           float* __restrict__ h, float* __restrict__ xv, float* __restrict__ rbf) {
    int p = blockIdx.x, lane = threadIdx.x;
    int e = perm[p];
    int4 me = metaO[e];
    if (lane == 0) meta2[p] = me;
    h[p * DM + lane]      = ef[e * DM + lane];
    h[p * DM + 64 + lane] = ef[e * DM + 64 + lane];
    if (lane < 4) xv[p * 4 + lane] = (lane < 3) ? ec[e * 3 + lane] : 0.f;
    float dx = nc[me.y * 3 + 0] - nc[me.x * 3 + 0];
    float dy = nc[me.y * 3 + 1] - nc[me.x * 3 + 1];
    float dz = nc[me.y * 3 + 2] - nc[me.x * 3 + 2];
    float dist = sqrtf(dx * dx + dy * dy + dz * dz);
    float t = fminf(fmaxf(dist / CUT, 0.f), 1.f);
    float fc = 0.5f * (cosf(3.14159265358979f * t) + 1.f);
    float width = CUT / NR;
    float center = (CUT * lane) / (NR - 1);
    float u = (dist - center) / width;
    rbf[p * NR + lane] = expf(-u * u) * fc;
}

// ---------------- inter neighbor lists ----------------
__global__ __launch_bounds__(64)
void build_lists(const int4* __restrict__ meta2,
                 u16* __restrict__ idx_e, int* __restrict__ cnt_e) {
    __shared__ int ce;
    __shared__ u16 be[CAP];
    int i = blockIdx.x, lane = threadIdx.x;
    if (lane == 0) ce = 0;
    __syncthreads();
    int4 mi = meta2[i];
    for (int j = lane; j < NE; j += 64) {
        int4 mj = meta2[j];
        bool intra_b = (mi.z == mj.z) && (mi.w == mj.w);
        bool share = (mi.x == mj.x) || (mi.x == mj.y) ||
                     (mi.y == mj.x) || (mi.y == mj.y);
        bool oke = (share && !intra_b) || (i == j);
        if (oke) { int p = atomicAdd(&ce, 1); if (p < CAP) be[p] = (u16)j; }
    }
    __syncthreads();
    int ne_ = min(ce, CAP);
    if (lane == 0) cnt_e[i] = ne_;
    for (int p = lane; p < ne_; p += 64) idx_e[i * CAP + p] = be[p];
}

// ---------------- intra attention: class-range neighbors, prefetched cached loads ----------------
// unit = tid>>2 (256 units = 32 rows x 8 heads), sub = tid&3
__device__ __forceinline__ void attn_intra(
    const short (&qsb)[BR][136], const u64* __restrict__ kvaL,
    const float* __restrict__ xr, const int4* __restrict__ meta2,
    const int* __restrict__ cls_start,
    short (&ob)[BR][136], float (&pxs)[NH][BR][3],
    int m0, int tid)
{
    int unit = tid >> 2, sub = tid & 3;
    int rowl = unit >> 3, head = unit & 7, row = m0 + rowl;
    const u64* q64 = reinterpret_cast<const u64*>(&qsb[rowl][head * HD]);
    u64 qc[4];
#pragma unroll
    for (int t = 0; t < 4; t++) qc[t] = q64[t];
    int4 mr = meta2[row];
    int c = mr.z * 16 + mr.w;
    int nb0 = cls_start[c], nb1 = cls_start[c + 1];

    float m = -1e30f, li = 0.f;
    float acc[HD + 3];
#pragma unroll
    for (int d = 0; d < HD + 3; d++) acc[d] = 0.f;

    int p2 = nb0 + sub;
    bool have = p2 < nb1;
    int pc = have ? p2 : nb0;
    const u64* kb = kvaL + ((size_t)head * NE + pc) * 8;
    u64 kc[4], vc[4];
#pragma unroll
    for (int t = 0; t < 4; t++) { kc[t] = kb[t]; vc[t] = kb[4 + t]; }
    float x0 = xr[pc * 4], x1 = xr[pc * 4 + 1], x2 = xr[pc * 4 + 2];

    while (have) {
        int pn = p2 + 4;
        bool haveN = pn < nb1;
        int pl = haveN ? pn : nb0;
        const u64* kbn = kvaL + ((size_t)head * NE + pl) * 8;
        u64 nk[4], nv[4];
#pragma unroll
        for (int t = 0; t < 4; t++) { nk[t] = kbn[t]; nv[t] = kbn[4 + t]; }
        float nx0 = xr[pl * 4], nx1 = xr[pl * 4 + 1], nx2 = xr[pl * 4 + 2];

        float s = 0.f;
#pragma unroll
        for (int t = 0; t < 4; t++)
#pragma unroll
            for (int i = 0; i < 4; i++) s += bfx(qc[t], i) * bfx(kc[t], i);
        s *= 0.25f;
        if (s > m) {
            float cr = __expf(m - s);
            m = s; li *= cr;
#pragma unroll
            for (int d = 0; d < HD + 3; d++) acc[d] *= cr;
        }
        float pw = __expf(s - m);
        li += pw;
#pragma unroll
        for (int t = 0; t < 4; t++)
#pragma unroll
            for (int i = 0; i < 4; i++) acc[t * 4 + i] += pw * bfx(vc[t], i);
        acc[HD] += pw * x0; acc[HD + 1] += pw * x1; acc[HD + 2] += pw * x2;

        p2 = pn; have = haveN;
#pragma unroll
        for (int t = 0; t < 4; t++) { kc[t] = nk[t]; vc[t] = nv[t]; }
        x0 = nx0; x1 = nx1; x2 = nx2;
    }

    float mA = fmaxf(m, __shfl_xor(m, 1));
    mA = fmaxf(mA, __shfl_xor(mA, 2));
    float cf = __expf(m - mA);
    li *= cf;
#pragma unroll
    for (int d = 0; d < HD + 3; d++) acc[d] *= cf;
#pragma unroll
    for (int off = 1; off <= 2; off <<= 1) {
        li += __shfl_xor(li, off);
#pragma unroll
        for (int d = 0; d < HD + 3; d++) acc[d] += __shfl_xor(acc[d], off);
    }
    if (sub == 0) {
        float inv = 1.f / li;
#pragma unroll
        for (int d = 0; d < HD; d += 2) {
            unsigned loq = (u16)f2b(acc[d] * inv);
            unsigned hiq = (u16)f2b(acc[d + 1] * inv);
            *reinterpret_cast<unsigned*>(&ob[rowl][head * HD + d]) = loq | (hiq << 16);
        }
        pxs[head][rowl][0] = acc[HD] * inv;
        pxs[head][rowl][1] = acc[HD + 1] * inv;
        pxs[head][rowl][2] = acc[HD + 2] * inv;
    }
}

// ---------------- inter attention: prefetched cached gathers ----------------
__device__ __forceinline__ void attn_inter(
    const short (&qsb)[BR][136], const u64* __restrict__ kveL,
    const u16* __restrict__ idx, const int* __restrict__ cnt,
    short (&ob)[BR][136], int m0, int tid)
{
    int unit = tid >> 2, sub = tid & 3;
    int rowl = unit >> 3, head = unit & 7, row = m0 + rowl;
    const u64* q64 = reinterpret_cast<const u64*>(&qsb[rowl][head * HD]);
    u64 qc[4];
#pragma unroll
    for (int t = 0; t < 4; t++) qc[t] = q64[t];
    const u64* kvh = kveL + (size_t)head * NE * 8;
    int n = cnt[row];
    float m = -1e30f, li = 0.f;
    float acc[HD];
#pragma unroll
    for (int d = 0; d < HD; d++) acc[d] = 0.f;

    int p = sub;
    bool have = p < n;
    int jc = have ? (int)idx[row * CAP + p] : 0;
    const u64* kb = kvh + (size_t)jc * 8;
    u64 kc[4], vc[4];
#pragma unroll
    for (int t = 0; t < 4; t++) { kc[t] = kb[t]; vc[t] = kb[4 + t]; }

    while (have) {
        int pn = p + 4;
        bool haveN = pn < n;
        int jn = haveN ? (int)idx[row * CAP + pn] : 0;
        const u64* kbn = kvh + (size_t)jn * 8;
        u64 nk[4], nv[4];
#pragma unroll
        for (int t = 0; t < 4; t++) { nk[t] = kbn[t]; nv[t] = kbn[4 + t]; }

        float s = 0.f;
#pragma unroll
        for (int t = 0; t < 4; t++)
#pragma unroll
            for (int i = 0; i < 4; i++) s += bfx(qc[t], i) * bfx(kc[t], i);
        s *= 0.25f;
        if (s > m) {
            float cr = __expf(m - s);
            m = s; li *= cr;
#pragma unroll
            for (int d = 0; d < HD; d++) acc[d] *= cr;
        }
        float pw = __expf(s - m);
        li += pw;
#pragma unroll
        for (int t = 0; t < 4; t++)
#pragma unroll
            for (int i = 0; i < 4; i++) acc[t * 4 + i] += pw * bfx(vc[t], i);

        p = pn; have = haveN;
#pragma unroll
        for (int t = 0; t < 4; t++) { kc[t] = nk[t]; vc[t] = nv[t]; }
    }

    float mA = fmaxf(m, __shfl_xor(m, 1));
    mA = fmaxf(mA, __shfl_xor(mA, 2));
    float cf = __expf(m - mA);
    li *= cf;
#pragma unroll
    for (int d = 0; d < HD; d++) acc[d] *= cf;
#pragma unroll
    for (int off = 1; off <= 2; off <<= 1) {
        li += __shfl_xor(li, off);
#pragma unroll
        for (int d = 0; d < HD; d++) acc[d] += __shfl_xor(acc[d], off);
    }
    if (sub == 0) {
        float inv = 1.f / li;
#pragma unroll
        for (int d = 0; d < HD; d += 2) {
            unsigned loq = (u16)f2b(acc[d] * inv);
            unsigned hiq = (u16)f2b(acc[d + 1] * inv);
            *reinterpret_cast<unsigned*>(&ob[rowl][head * HD + d]) = loq | (hiq << 16);
        }
    }
}

// LN over row pair (wave w: rows 2w, 2w+1; 16 waves cover 32 rows)
__device__ __forceinline__ void ln_rows(float (&zs)[BR][132], float (&hF)[BR][132],
                                        short* hB, const float* g, const float* b,
                                        int w, int l) {
#pragma unroll
    for (int rr = 0; rr < 2; rr++) {
        int r = 2 * w + rr;
        float z0 = zs[r][l], z1 = zs[r][64 + l];
        float s = z0 + z1;
#pragma unroll
        for (int off = 32; off; off >>= 1) s += __shfl_xor(s, off);
        float mean = s * (1.f / DM);
        float d0 = z0 - mean, d1 = z1 - mean;
        float vs = d0 * d0 + d1 * d1;
#pragma unroll
        for (int off = 32; off; off >>= 1) vs += __shfl_xor(vs, off);
        float inv = rsqrtf(vs * (1.f / DM) + 1e-5f);
        float h0 = d0 * inv * g[l] + b[l];
        float h1 = d1 * inv * g[64 + l] + b[64 + l];
        hF[r][l] = h0; hF[r][64 + l] = h1;
        hB[r * 136 + l] = f2b(h0);
        hB[r * 136 + 64 + l] = f2b(h1);
    }
}

// ---------------- persistent mega kernel (32 rows/block, 96 blocks, 16 waves, 4 waves/SIMD) ----------------
__global__ __launch_bounds__(THREADS, 4)
void mega_kernel(const float* __restrict__ h_init, const float* __restrict__ rbf_g,
                 const int4* __restrict__ meta2, const int* __restrict__ cls_start,
                 const int* __restrict__ perm,
                 const u16* __restrict__ idx_e, const int* __restrict__ cnt_e,
                 const short* __restrict__ pk,
                 const float* __restrict__ b1g, const float* __restrict__ b2g,
                 const float* __restrict__ ln1g, const float* __restrict__ ln1b,
                 const float* __restrict__ ln2g, const float* __restrict__ ln2b,
                 const float* __restrict__ ln3g, const float* __restrict__ ln3b,
                 const float* __restrict__ Wcg, const float* __restrict__ bcg,
                 short* __restrict__ kva, short* __restrict__ kve,
                 float* __restrict__ xv, int* __restrict__ barcnt,
                 float* __restrict__ outp)
{
    __shared__ float hL[BR][132];
    __shared__ float hn[BR][132];
    __shared__ float zs[BR][132];
    __shared__ short qsb[BR][136];
    __shared__ short hb[BR][136];
    __shared__ short hnb[BR][136];
    __shared__ short ob[BR][136];
    __shared__ short rbfb[BR][72];
    __shared__ short ub[BR][520];
    __shared__ float pxs[NH][BR][3];

    int tid = threadIdx.x, w = tid >> 6, l = tid & 63;
    int m0 = blockIdx.x * BR;
    int R4 = 4 * (l >> 4), c0 = l & 15;
    int rt = w >> 3, ct = w & 7;        // row-tile, col-tile for 32x128 outputs
    int rb = rt * 16;                    // row base

    for (int i = tid; i < BR * 128; i += THREADS) hL[i >> 7][i & 127] = h_init[m0 * DM + i];
    for (int i = tid; i < BR * 64; i += THREADS) rbfb[i >> 6][i & 63] = f2b(rbf_g[m0 * NR + i]);
    __syncthreads();

    int ph = 0;
    for (int lay = 0; lay < NL; lay++) {
        const short* Lb = pk + (size_t)lay * PK_LAYER;
        const float* xr = xv + (size_t)lay * NE * 4;
        float* xw2 = xv + (size_t)(lay + 1) * NE * 4;
        u64* kvaL = reinterpret_cast<u64*>(kva) + (size_t)lay * NH * NE * 8;
        u64* kveL = reinterpret_cast<u64*>(kve) + (size_t)lay * NH * NE * 8;
        bool last = (lay == NL - 1);

        // P1a: hn = hL + rbf@Wrbf  (16 tiles: wave (rt,ct))
        {
            f32x4 acc = tileAb<2, 72>(&rbfb[rb][0], Lb + PK_WRBF + ct * 1024, l);
#pragma unroll
            for (int r = 0; r < 4; r++) {
                float z = acc[r] + hL[rb + R4 + r][ct * 16 + c0];
                hn[rb + R4 + r][ct * 16 + c0] = z;
                hnb[rb + R4 + r][ct * 16 + c0] = f2b(z);
            }
        }
        __syncthreads();
        // P1b: q->LDS(bf16); fused k|v -> kvaL (write-through)
        {
            f32x4 aq = tileAb<4, 136>(&hnb[rb][0], Lb + PK_QKV_A + 0 * 16384 + ct * 2048, l);
#pragma unroll
            for (int r = 0; r < 4; r++) qsb[rb + R4 + r][ct * 16 + c0] = f2b(aq[r]);
            f32x4 ak = tileAb<4, 136>(&hnb[rb][0], Lb + PK_QKV_A + 1 * 16384 + ct * 2048, l);
            f32x4 av = tileAb<4, 136>(&hnb[rb][0], Lb + PK_QKV_A + 2 * 16384 + ct * 2048, l);
#pragma unroll
            for (int r = 0; r < 4; r++) {
                ub[rb + R4 + r][ct * 16 + c0] = f2b(ak[r]);
                ub[rb + R4 + r][128 + ct * 16 + c0] = f2b(av[r]);
            }
            __syncthreads();
            for (int u = tid; u < BR * 64; u += THREADS) {
                int r = u >> 6, rest = u & 63, hh = rest >> 3, j = rest & 7;
                int so = (j < 4) ? (hh * 16 + j * 4) : (128 + hh * 16 + (j - 4) * 4);
                u64 val = *reinterpret_cast<const u64*>(&ub[r][so]);
                ast64(kvaL + ((size_t)hh * NE + m0 + r) * 8 + j, val);
            }
        }
        gbar(barcnt, GRID * (++ph));

        // P2: intra attn + Wo + LN1
        attn_intra(qsb, kvaL, xr, meta2, cls_start, ob, pxs, m0, tid);
        __syncthreads();
        {
            f32x4 d = tileAb<4, 136>(&ob[rb][0], Lb + PK_WO_A + ct * 2048, l);
#pragma unroll
            for (int r = 0; r < 4; r++)
                zs[rb + R4 + r][ct * 16 + c0] = d[r] + hn[rb + R4 + r][ct * 16 + c0];
        }
        __syncthreads();
        ln_rows(zs, hL, &hb[0][0], ln1g + lay * DM, ln1b + lay * DM, w, l);
        __syncthreads();

        // P3: qkv_e -> kveL
        {
            f32x4 aq = tileAb<4, 136>(&hb[rb][0], Lb + PK_QKV_E + 0 * 16384 + ct * 2048, l);
#pragma unroll
            for (int r = 0; r < 4; r++) qsb[rb + R4 + r][ct * 16 + c0] = f2b(aq[r]);
            f32x4 ak = tileAb<4, 136>(&hb[rb][0], Lb + PK_QKV_E + 1 * 16384 + ct * 2048, l);
            f32x4 av = tileAb<4, 136>(&hb[rb][0], Lb + PK_QKV_E + 2 * 16384 + ct * 2048, l);
#pragma unroll
            for (int r = 0; r < 4; r++) {
                ub[rb + R4 + r][ct * 16 + c0] = f2b(ak[r]);
                ub[rb + R4 + r][128 + ct * 16 + c0] = f2b(av[r]);
            }
            __syncthreads();
            for (int u = tid; u < BR * 64; u += THREADS) {
                int r = u >> 6, rest = u & 63, hh = rest >> 3, j = rest & 7;
                int so = (j < 4) ? (hh * 16 + j * 4) : (128 + hh * 16 + (j - 4) * 4);
                u64 val = *reinterpret_cast<const u64*>(&ub[r][so]);
                ast64(kveL + ((size_t)hh * NE + m0 + r) * 8 + j, val);
            }
        }
        gbar(barcnt, GRID * (++ph));

        // P4: inter attn + Wo + LN2
        attn_inter(qsb, kveL, idx_e, cnt_e, ob, m0, tid);
        __syncthreads();
        {
            f32x4 d = tileAb<4, 136>(&ob[rb][0], Lb + PK_WO_E + ct * 2048, l);
#pragma unroll
            for (int r = 0; r < 4; r++)
                zs[rb + R4 + r][ct * 16 + c0] = d[r] + hL[rb + R4 + r][ct * 16 + c0];
        }
        __syncthreads();
        ln_rows(zs, hL, &hb[0][0], ln2g + lay * DM, ln2b + lay * DM, w, l);
        __syncthreads();

        // P5: FFN1 -> ub  (64 tiles: t = w*4+j, rtt=t>>5, ctt=t&31)
#pragma unroll
        for (int j = 0; j < 4; j++) {
            int t = w * 4 + j;
            int rtt = t >> 5, ctt = t & 31;
            f32x4 acc = tileAb<4, 136>(&hb[rtt * 16][0], Lb + PK_W1 + ctt * 2048, l);
#pragma unroll
            for (int r = 0; r < 4; r++) {
                int col = ctt * 16 + c0;
                float xvv = acc[r] + b1g[lay * FF + col];
                xvv = xvv / (1.f + __expf(-xvv));
                ub[rtt * 16 + R4 + r][col] = f2b(xvv);
            }
        }
        __syncthreads();
        // FFN2 -> zs  (16 tiles: wave (rt,ct), K=512)
        {
            f32x4 acc = tileAb<16, 520>(&ub[rb][0], Lb + PK_W2 + ct * 8192, l);
#pragma unroll
            for (int r = 0; r < 4; r++)
                zs[rb + R4 + r][ct * 16 + c0] = acc[r] + b2g[lay * DM + ct * 16 + c0]
                                              + hL[rb + R4 + r][ct * 16 + c0];
        }
        __syncthreads();
        // LN3 + gate + coord (wave w: rows 2w, 2w+1)
        {
            const float* g3 = ln3g + lay * DM;
            const float* b3 = ln3b + lay * DM;
            const float* Wcl = Wcg + lay * DM;
            float bc0 = bcg[lay];
#pragma unroll
            for (int rr = 0; rr < 2; rr++) {
                int r = 2 * w + rr, row = m0 + r;
                int orow = perm[row];
                float z0 = zs[r][l], z1 = zs[r][64 + l];
                float s = z0 + z1;
#pragma unroll
                for (int off = 32; off; off >>= 1) s += __shfl_xor(s, off);
                float mean = s * (1.f / DM);
                float d0 = z0 - mean, d1 = z1 - mean;
                float vsum = d0 * d0 + d1 * d1;
#pragma unroll
                for (int off = 32; off; off >>= 1) vsum += __shfl_xor(vsum, off);
                float inv = rsqrtf(vsum * (1.f / DM) + 1e-5f);
                float h0 = d0 * inv * g3[l] + b3[l];
                float h1 = d1 * inv * g3[64 + l] + b3[64 + l];
                hL[r][l] = h0; hL[r][64 + l] = h1;
                if (last) { outp[orow * DM + l] = h0; outp[orow * DM + 64 + l] = h1; }
                float dc = h0 * Wcl[l] + h1 * Wcl[64 + l];
#pragma unroll
                for (int off = 32; off; off >>= 1) dc += __shfl_xor(dc, off);
                float gate = tanhf(dc + bc0);
                if (l < 3) {
                    float pxm = 0.f;
#pragma unroll
                    for (int hh = 0; hh < NH; hh++) pxm += pxs[hh][r][l];
                    pxm *= 0.125f;
                    float xvv = xr[row * 4 + l];
                    float nx = xvv + gate * (xvv - pxm);
                    astf(xw2 + row * 4 + l, nx);
                    if (last) outp[NE * DM + orow * 3 + l] = nx;
                }
            }
        }
        __syncthreads();
    }
}

extern "C" void kernel_launch(void* const* d_in, const int* in_sizes, int n_in,
                              void* d_out, int out_size, void* d_ws, size_t ws_size,
                              hipStream_t stream) {
    const float* ef   = (const float*)d_in[0];
    const float* ec   = (const float*)d_in[1];
    const int*   eidx = (const int*)d_in[2];
    const float* nc   = (const float*)d_in[3];
    const int*   bids = (const int*)d_in[4];
    const float* b1   = (const float*)d_in[14];
    const float* b2   = (const float*)d_in[16];
    const float* ln1g = (const float*)d_in[17];
    const float* ln1b = (const float*)d_in[18];
    const float* ln2g = (const float*)d_in[19];
    const float* ln2b = (const float*)d_in[20];
    const float* ln3g = (const float*)d_in[21];
    const float* ln3b = (const float*)d_in[22];
    const float* Wc   = (const float*)d_in[24];
    const float* bc   = (const float*)d_in[25];
    float* out = (float*)d_out;

    char* w = (char*)d_ws;
    auto carve = [&](size_t bytes) { char* p = w; w += ((bytes + 255) / 256) * 256; return p; };
    int*   barcnt = (int*)carve(256);
    int*   hist   = (int*)carve(NCLS * 4);
    int*   csta   = (int*)carve((NCLS + 1) * 4);
    int*   fill   = (int*)carve(NCLS * 4);
    int*   key    = (int*)carve((size_t)NE * 4);
    int*   perm   = (int*)carve((size_t)NE * 4);
    int4*  metaO  = (int4*)carve((size_t)NE * 16);
    int4*  meta2  = (int4*)carve((size_t)NE * 16);
    float* xv     = (float*)carve((size_t)(NL + 1) * NE * 4 * 4);
    int*   cnt_e  = (int*)carve((size_t)NE * 4);
    u16*   idx_e  = (u16*)carve((size_t)NE * CAP * 2);
    float* rbf_g  = (float*)carve((size_t)NE * NR * 4);
    float* h_in   = (float*)carve((size_t)NE * DM * 4);
    short* kva    = (short*)carve((size_t)NL * NH * NE * 32 * 2);
    short* kve    = (short*)carve((size_t)NL * NH * NE * 32 * 2);
    short* pk     = (short*)carve((size_t)NL * PK_LAYER * 2);

    WSrc ws;
    ws.W[0] = (const float*)d_in[5];   ws.W[1] = (const float*)d_in[6];
    ws.W[2] = (const float*)d_in[7];   ws.W[3] = (const float*)d_in[8];
    ws.W[4] = (const float*)d_in[9];   ws.W[5] = (const float*)d_in[10];
    ws.W[6] = (const float*)d_in[11];  ws.W[7] = (const float*)d_in[12];
    ws.W[8] = (const float*)d_in[13];  ws.W[9] = (const float*)d_in[15];
    ws.W[10] = (const float*)d_in[23];
    pack_w<<<(NL * PK_LAYER + 255) / 256, 256, 0, stream>>>(ws, pk);

    zero_hist<<<1, 256, 0, stream>>>(hist, barcnt);
    k_meta<<<(NE + 255) / 256, 256, 0, stream>>>(eidx, bids, metaO, key, hist);
    k_scan<<<1, 256, 0, stream>>>(hist, csta, fill);
    k_scatter<<<(NE + 255) / 256, 256, 0, stream>>>(key, fill, perm);
    prep2<<<NE, 64, 0, stream>>>(ef, ec, nc, perm, metaO, meta2, h_in, xv, rbf_g);
    build_lists<<<NE, 64, 0, stream>>>(meta2, idx_e, cnt_e);

    mega_kernel<<<GRID, THREADS, 0, stream>>>(h_in, rbf_g, meta2, csta, perm,
                                              idx_e, cnt_e, pk,
                                              b1, b2, ln1g, ln1b, ln2g, ln2b, ln3g, ln3b,
                                              Wc, bc, kva, kve, xv, barcnt, out);
}

// Round 21
// 160.089 us; speedup vs baseline: 1.2482x; 1.2422x over previous
//
#include <hip/hip_runtime.h>
#include <hip/hip_bf16.h>

typedef unsigned short u16;
typedef unsigned long long u64;
typedef __attribute__((ext_vector_type(4))) float f32x4;
typedef __attribute__((ext_vector_type(8))) short bf16x8;

#define NE 3072
#define DM 128
#define NH 8
#define HD 16
#define NL 3
#define NR 64
#define FF 512
#define CUT 10.0f
#define CAP 96
#define GRID 192
#define BR 16
#define NCLS 256

#define PK_QKV_A 0
#define PK_WO_A  49152
#define PK_QKV_E 65536
#define PK_WO_E  114688
#define PK_W1    131072
#define PK_W2    196608
#define PK_WRBF  262144
#define PK_LAYER 270336

__device__ __forceinline__ short f2b(float f) {
    union { __hip_bfloat16 b; short s; } u;
    u.b = __float2bfloat16(f);
    return u.s;
}
__device__ __forceinline__ void ast64(u64* p, u64 v) {
    __hip_atomic_store(p, v, __ATOMIC_RELAXED, __HIP_MEMORY_SCOPE_AGENT);
}
__device__ __forceinline__ void astf(float* p, float v) {
    __hip_atomic_store(p, v, __ATOMIC_RELAXED, __HIP_MEMORY_SCOPE_AGENT);
}
__device__ __forceinline__ float bfx(u64 v, int i) {
    return __uint_as_float(((unsigned)(v >> (16 * i)) & 0xFFFFu) << 16);
}

// 16x16 MFMA tile: A bf16 from LDS (stride S shorts), B packed bf16
template <int KT, int S>
__device__ __forceinline__ f32x4 tileAb(const short* As, const short* Bt, int l) {
    f32x4 acc = {0.f, 0.f, 0.f, 0.f};
#pragma unroll
    for (int kt = 0; kt < KT; kt++) {
        bf16x8 av = *(const bf16x8*)(As + (l & 15) * S + kt * 32 + 8 * (l >> 4));
        bf16x8 bv = *(const bf16x8*)(Bt + kt * 512 + l * 8);
        acc = __builtin_amdgcn_mfma_f32_16x16x32_bf16(av, bv, acc, 0, 0, 0);
    }
    return acc;
}

// grid barrier: release-add, relaxed poll
__device__ __forceinline__ void gbar(int* cnt, int target) {
    __syncthreads();
    if (threadIdx.x == 0) {
        __hip_atomic_fetch_add(cnt, 1, __ATOMIC_RELEASE, __HIP_MEMORY_SCOPE_AGENT);
        while (__hip_atomic_load(cnt, __ATOMIC_RELAXED, __HIP_MEMORY_SCOPE_AGENT) < target)
            __builtin_amdgcn_s_sleep(2);
        asm volatile("" ::: "memory");
    }
    __syncthreads();
}

// ---------------- weight pack ----------------
struct WSrc { const float* W[11]; };

__global__ __launch_bounds__(256)
void pack_w(WSrc ws, short* __restrict__ dst) {
    int gid = blockIdx.x * 256 + threadIdx.x;
    if (gid >= NL * PK_LAYER) return;
    int layer = gid / PK_LAYER, e = gid % PK_LAYER;
    int kind, off, K, N;
    if (e < 49152)       { kind = e / 16384;            off = e % 16384;      K = 128; N = 128; }
    else if (e < 65536)  { kind = 3;                    off = e - 49152;      K = 128; N = 128; }
    else if (e < 114688) { kind = 4 + (e - 65536) / 16384; off = (e - 65536) % 16384; K = 128; N = 128; }
    else if (e < 131072) { kind = 7;                    off = e - 114688;     K = 128; N = 128; }
    else if (e < 196608) { kind = 8;                    off = e - 131072;     K = 128; N = 512; }
    else if (e < 262144) { kind = 9;                    off = e - 196608;     K = 512; N = 128; }
    else                 { kind = 10;                   off = e - 262144;     K = 64;  N = 128; }
    int i = off & 7, lane = (off >> 3) & 63, ft = off >> 9;
    int KT = K >> 5;
    int kt = ft % KT, nt = ft / KT;
    int n = nt * 16 + (lane & 15);
    int k = kt * 32 + 8 * (lane >> 4) + i;
    const float* W = ws.W[kind] + (size_t)layer * K * N;
    dst[gid] = f2b(W[k * N + n]);
}

// ---------------- sort machinery ----------------
__global__ void zero_hist(int* hist, int* barcnt) {
    hist[threadIdx.x] = 0;
    if (threadIdx.x == 0) *barcnt = 0;
}

__global__ __launch_bounds__(256)
void k_meta(const int* __restrict__ eidx, const int* __restrict__ bids,
            int4* __restrict__ meta, int* __restrict__ key, int* __restrict__ hist) {
    int e = blockIdx.x * 256 + threadIdx.x;
    if (e >= NE) return;
    int s = eidx[e], d = eidx[NE + e];
    int bs = bids[s], bd = bids[d];
    meta[e] = make_int4(s, d, bs, bd);
    int kk = bs * 16 + bd;
    key[e] = kk;
    atomicAdd(&hist[kk], 1);
}

__global__ __launch_bounds__(256)
void k_scan(const int* __restrict__ hist, int* __restrict__ cls_start,
            int* __restrict__ fill) {
    __shared__ int sh[NCLS];
    int t = threadIdx.x;
    sh[t] = hist[t];
    __syncthreads();
    for (int off = 1; off < NCLS; off <<= 1) {
        int v = (t >= off) ? sh[t - off] : 0;
        __syncthreads();
        sh[t] += v;
        __syncthreads();
    }
    cls_start[t + 1] = sh[t];
    if (t == 0) cls_start[0] = 0;
    fill[t] = sh[t] - hist[t];
}

__global__ __launch_bounds__(256)
void k_scatter(const int* __restrict__ key, int* __restrict__ fill,
               int* __restrict__ perm) {
    int e = blockIdx.x * 256 + threadIdx.x;
    if (e >= NE) return;
    int pos = atomicAdd(&fill[key[e]], 1);
    perm[pos] = e;
}

// ---------------- prep in permuted order ----------------
__global__ __launch_bounds__(64)
void prep2(const float* __restrict__ ef, const float* __restrict__ ec,
           const float* __restrict__ nc, const int* __restrict__ perm,
           const int4* __restrict__ metaO, int4* __restrict__ meta2,
           float* __restrict__ h, float* __restrict__ xv, float* __restrict__ rbf) {
    int p = blockIdx.x, lane = threadIdx.x;
    int e = perm[p];
    int4 me = metaO[e];
    if (lane == 0) meta2[p] = me;
    h[p * DM + lane]      = ef[e * DM + lane];
    h[p * DM + 64 + lane] = ef[e * DM + 64 + lane];
    if (lane < 4) xv[p * 4 + lane] = (lane < 3) ? ec[e * 3 + lane] : 0.f;
    float dx = nc[me.y * 3 + 0] - nc[me.x * 3 + 0];
    float dy = nc[me.y * 3 + 1] - nc[me.x * 3 + 1];
    float dz = nc[me.y * 3 + 2] - nc[me.x * 3 + 2];
    float dist = sqrtf(dx * dx + dy * dy + dz * dz);
    float t = fminf(fmaxf(dist / CUT, 0.f), 1.f);
    float fc = 0.5f * (cosf(3.14159265358979f * t) + 1.f);
    float width = CUT / NR;
    float center = (CUT * lane) / (NR - 1);
    float u = (dist - center) / width;
    rbf[p * NR + lane] = expf(-u * u) * fc;
}

// ---------------- inter neighbor lists ----------------
__global__ __launch_bounds__(64)
void build_lists(const int4* __restrict__ meta2,
                 u16* __restrict__ idx_e, int* __restrict__ cnt_e) {
    __shared__ int ce;
    __shared__ u16 be[CAP];
    int i = blockIdx.x, lane = threadIdx.x;
    if (lane == 0) ce = 0;
    __syncthreads();
    int4 mi = meta2[i];
    for (int j = lane; j < NE; j += 64) {
        int4 mj = meta2[j];
        bool intra_b = (mi.z == mj.z) && (mi.w == mj.w);
        bool share = (mi.x == mj.x) || (mi.x == mj.y) ||
                     (mi.y == mj.x) || (mi.y == mj.y);
        bool oke = (share && !intra_b) || (i == j);
        if (oke) { int p = atomicAdd(&ce, 1); if (p < CAP) be[p] = (u16)j; }
    }
    __syncthreads();
    int ne_ = min(ce, CAP);
    if (lane == 0) cnt_e[i] = ne_;
    for (int p = lane; p < ne_; p += 64) idx_e[i * CAP + p] = be[p];
}

// ---------------- intra attention: class-range neighbors, prefetched cached loads ----------------
__device__ __forceinline__ void attn_intra(
    const short (&qsb)[BR][136], const u64* __restrict__ kvaL,
    const float* __restrict__ xr, const int4* __restrict__ meta2,
    const int* __restrict__ cls_start,
    short (&ob)[BR][136], float (&pxs)[NH][BR][3],
    int m0, int w, int l)
{
    int rowl = l >> 2, sub = l & 3, row = m0 + rowl;
    const u64* q64 = reinterpret_cast<const u64*>(&qsb[rowl][w * HD]);
    u64 qc[4];
#pragma unroll
    for (int t = 0; t < 4; t++) qc[t] = q64[t];
    int4 mr = meta2[row];
    int c = mr.z * 16 + mr.w;
    int nb0 = cls_start[c], nb1 = cls_start[c + 1];

    float m = -1e30f, li = 0.f;
    float acc[HD + 3];
#pragma unroll
    for (int d = 0; d < HD + 3; d++) acc[d] = 0.f;

    int p2 = nb0 + sub;
    bool have = p2 < nb1;
    int pc = have ? p2 : nb0;
    const u64* kb = kvaL + ((size_t)w * NE + pc) * 8;
    u64 kc[4], vc[4];
#pragma unroll
    for (int t = 0; t < 4; t++) { kc[t] = kb[t]; vc[t] = kb[4 + t]; }
    float x0 = xr[pc * 4], x1 = xr[pc * 4 + 1], x2 = xr[pc * 4 + 2];

    while (have) {
        int pn = p2 + 4;
        bool haveN = pn < nb1;
        int pl = haveN ? pn : nb0;
        const u64* kbn = kvaL + ((size_t)w * NE + pl) * 8;
        u64 nk[4], nv[4];
#pragma unroll
        for (int t = 0; t < 4; t++) { nk[t] = kbn[t]; nv[t] = kbn[4 + t]; }
        float nx0 = xr[pl * 4], nx1 = xr[pl * 4 + 1], nx2 = xr[pl * 4 + 2];

        float s = 0.f;
#pragma unroll
        for (int t = 0; t < 4; t++)
#pragma unroll
            for (int i = 0; i < 4; i++) s += bfx(qc[t], i) * bfx(kc[t], i);
        s *= 0.25f;
        if (s > m) {
            float cr = __expf(m - s);
            m = s; li *= cr;
#pragma unroll
            for (int d = 0; d < HD + 3; d++) acc[d] *= cr;
        }
        float pw = __expf(s - m);
        li += pw;
#pragma unroll
        for (int t = 0; t < 4; t++)
#pragma unroll
            for (int i = 0; i < 4; i++) acc[t * 4 + i] += pw * bfx(vc[t], i);
        acc[HD] += pw * x0; acc[HD + 1] += pw * x1; acc[HD + 2] += pw * x2;

        p2 = pn; have = haveN;
#pragma unroll
        for (int t = 0; t < 4; t++) { kc[t] = nk[t]; vc[t] = nv[t]; }
        x0 = nx0; x1 = nx1; x2 = nx2;
    }

    float mA = fmaxf(m, __shfl_xor(m, 1));
    mA = fmaxf(mA, __shfl_xor(mA, 2));
    float cf = __expf(m - mA);
    li *= cf;
#pragma unroll
    for (int d = 0; d < HD + 3; d++) acc[d] *= cf;
#pragma unroll
    for (int off = 1; off <= 2; off <<= 1) {
        li += __shfl_xor(li, off);
#pragma unroll
        for (int d = 0; d < HD + 3; d++) acc[d] += __shfl_xor(acc[d], off);
    }
    if (sub == 0) {
        float inv = 1.f / li;
#pragma unroll
        for (int d = 0; d < HD; d += 2) {
            unsigned loq = (u16)f2b(acc[d] * inv);
            unsigned hiq = (u16)f2b(acc[d + 1] * inv);
            *reinterpret_cast<unsigned*>(&ob[rowl][w * HD + d]) = loq | (hiq << 16);
        }
        pxs[w][rowl][0] = acc[HD] * inv;
        pxs[w][rowl][1] = acc[HD + 1] * inv;
        pxs[w][rowl][2] = acc[HD + 2] * inv;
    }
}

// ---------------- inter attention: prefetched cached gathers ----------------
__device__ __forceinline__ void attn_inter(
    const short (&qsb)[BR][136], const u64* __restrict__ kveL,
    const u16* __restrict__ idx, const int* __restrict__ cnt,
    short (&ob)[BR][136], int m0, int w, int l)
{
    int rowl = l >> 2, sub = l & 3, row = m0 + rowl;
    const u64* q64 = reinterpret_cast<const u64*>(&qsb[rowl][w * HD]);
    u64 qc[4];
#pragma unroll
    for (int t = 0; t < 4; t++) qc[t] = q64[t];
    const u64* kvh = kveL + (size_t)w * NE * 8;
    int n = cnt[row];
    float m = -1e30f, li = 0.f;
    float acc[HD];
#pragma unroll
    for (int d = 0; d < HD; d++) acc[d] = 0.f;

    int p = sub;
    bool have = p < n;
    int jc = have ? (int)idx[row * CAP + p] : 0;
    const u64* kb = kvh + (size_t)jc * 8;
    u64 kc[4], vc[4];
#pragma unroll
    for (int t = 0; t < 4; t++) { kc[t] = kb[t]; vc[t] = kb[4 + t]; }

    while (have) {
        int pn = p + 4;
        bool haveN = pn < n;
        int jn = haveN ? (int)idx[row * CAP + pn] : 0;
        const u64* kbn = kvh + (size_t)jn * 8;
        u64 nk[4], nv[4];
#pragma unroll
        for (int t = 0; t < 4; t++) { nk[t] = kbn[t]; nv[t] = kbn[4 + t]; }

        float s = 0.f;
#pragma unroll
        for (int t = 0; t < 4; t++)
#pragma unroll
            for (int i = 0; i < 4; i++) s += bfx(qc[t], i) * bfx(kc[t], i);
        s *= 0.25f;
        if (s > m) {
            float cr = __expf(m - s);
            m = s; li *= cr;
#pragma unroll
            for (int d = 0; d < HD; d++) acc[d] *= cr;
        }
        float pw = __expf(s - m);
        li += pw;
#pragma unroll
        for (int t = 0; t < 4; t++)
#pragma unroll
            for (int i = 0; i < 4; i++) acc[t * 4 + i] += pw * bfx(vc[t], i);

        p = pn; have = haveN;
#pragma unroll
        for (int t = 0; t < 4; t++) { kc[t] = nk[t]; vc[t] = nv[t]; }
    }

    float mA = fmaxf(m, __shfl_xor(m, 1));
    mA = fmaxf(mA, __shfl_xor(mA, 2));
    float cf = __expf(m - mA);
    li *= cf;
#pragma unroll
    for (int d = 0; d < HD; d++) acc[d] *= cf;
#pragma unroll
    for (int off = 1; off <= 2; off <<= 1) {
        li += __shfl_xor(li, off);
#pragma unroll
        for (int d = 0; d < HD; d++) acc[d] += __shfl_xor(acc[d], off);
    }
    if (sub == 0) {
        float inv = 1.f / li;
#pragma unroll
        for (int d = 0; d < HD; d += 2) {
            unsigned loq = (u16)f2b(acc[d] * inv);
            unsigned hiq = (u16)f2b(acc[d + 1] * inv);
            *reinterpret_cast<unsigned*>(&ob[rowl][w * HD + d]) = loq | (hiq << 16);
        }
    }
}

// LN over row pair (wave w: rows 2w, 2w+1)
__device__ __forceinline__ void ln_rows(float (&zs)[BR][132], float (&hF)[BR][132],
                                        short* hB, const float* g, const float* b,
                                        int w, int l) {
#pragma unroll
    for (int rr = 0; rr < 2; rr++) {
        int r = 2 * w + rr;
        float z0 = zs[r][l], z1 = zs[r][64 + l];
        float s = z0 + z1;
#pragma unroll
        for (int off = 32; off; off >>= 1) s += __shfl_xor(s, off);
        float mean = s * (1.f / DM);
        float d0 = z0 - mean, d1 = z1 - mean;
        float vs = d0 * d0 + d1 * d1;
#pragma unroll
        for (int off = 32; off; off >>= 1) vs += __shfl_xor(vs, off);
        float inv = rsqrtf(vs * (1.f / DM) + 1e-5f);
        float h0 = d0 * inv * g[l] + b[l];
        float h1 = d1 * inv * g[64 + l] + b[64 + l];
        hF[r][l] = h0; hF[r][64 + l] = h1;
        hB[r * 136 + l] = f2b(h0);
        hB[r * 136 + 64 + l] = f2b(h1);
    }
}

// ---------------- persistent mega kernel (16 rows/block, 192 blocks) ----------------
__global__ __launch_bounds__(512, 2)
void mega_kernel(const float* __restrict__ h_init, const float* __restrict__ rbf_g,
                 const int4* __restrict__ meta2, const int* __restrict__ cls_start,
                 const int* __restrict__ perm,
                 const u16* __restrict__ idx_e, const int* __restrict__ cnt_e,
                 const short* __restrict__ pk,
                 const float* __restrict__ b1g, const float* __restrict__ b2g,
                 const float* __restrict__ ln1g, const float* __restrict__ ln1b,
                 const float* __restrict__ ln2g, const float* __restrict__ ln2b,
                 const float* __restrict__ ln3g, const float* __restrict__ ln3b,
                 const float* __restrict__ Wcg, const float* __restrict__ bcg,
                 short* __restrict__ kva, short* __restrict__ kve,
                 float* __restrict__ xv, int* __restrict__ barcnt,
                 float* __restrict__ outp)
{
    __shared__ float hL[BR][132];
    __shared__ float hn[BR][132];
    __shared__ float zs[BR][132];
    __shared__ short qsb[BR][136];
    __shared__ short hb[BR][136];
    __shared__ short hnb[BR][136];
    __shared__ short ob[BR][136];
    __shared__ short rbfb[BR][72];
    __shared__ short ub[BR][520];
    __shared__ float pxs[NH][BR][3];

    int tid = threadIdx.x, w = tid >> 6, l = tid & 63;
    int m0 = blockIdx.x * BR;
    int R4 = 4 * (l >> 4), c0 = l & 15;

    for (int i = tid; i < BR * 128; i += 512) hL[i >> 7][i & 127] = h_init[m0 * DM + i];
    for (int i = tid; i < BR * 64; i += 512) rbfb[i >> 6][i & 63] = f2b(rbf_g[m0 * NR + i]);
    __syncthreads();

    int ph = 0;
    for (int lay = 0; lay < NL; lay++) {
        const short* Lb = pk + (size_t)lay * PK_LAYER;
        const float* xr = xv + (size_t)lay * NE * 4;
        float* xw2 = xv + (size_t)(lay + 1) * NE * 4;
        u64* kvaL = reinterpret_cast<u64*>(kva) + (size_t)lay * NH * NE * 8;
        u64* kveL = reinterpret_cast<u64*>(kve) + (size_t)lay * NH * NE * 8;
        bool last = (lay == NL - 1);

        // P1a: hn = hL + rbf@Wrbf
        {
            f32x4 acc = tileAb<2, 72>(&rbfb[0][0], Lb + PK_WRBF + w * 1024, l);
#pragma unroll
            for (int r = 0; r < 4; r++) {
                float z = acc[r] + hL[R4 + r][w * 16 + c0];
                hn[R4 + r][w * 16 + c0] = z;
                hnb[R4 + r][w * 16 + c0] = f2b(z);
            }
        }
        __syncthreads();
        // P1b: q->LDS(bf16); fused k|v -> kvaL (write-through)
        {
            f32x4 aq = tileAb<4, 136>(&hnb[0][0], Lb + PK_QKV_A + 0 * 16384 + w * 2048, l);
#pragma unroll
            for (int r = 0; r < 4; r++) qsb[R4 + r][w * 16 + c0] = f2b(aq[r]);
            f32x4 ak = tileAb<4, 136>(&hnb[0][0], Lb + PK_QKV_A + 1 * 16384 + w * 2048, l);
            f32x4 av = tileAb<4, 136>(&hnb[0][0], Lb + PK_QKV_A + 2 * 16384 + w * 2048, l);
#pragma unroll
            for (int r = 0; r < 4; r++) {
                ub[R4 + r][w * 16 + c0] = f2b(ak[r]);
                ub[R4 + r][128 + w * 16 + c0] = f2b(av[r]);
            }
            __syncthreads();
            for (int u = tid; u < BR * 64; u += 512) {
                int r = u >> 6, rest = u & 63, hh = rest >> 3, j = rest & 7;
                int so = (j < 4) ? (hh * 16 + j * 4) : (128 + hh * 16 + (j - 4) * 4);
                u64 val = *reinterpret_cast<const u64*>(&ub[r][so]);
                ast64(kvaL + ((size_t)hh * NE + m0 + r) * 8 + j, val);
            }
        }
        gbar(barcnt, GRID * (++ph));

        // P2: intra attn + Wo + LN1
        attn_intra(qsb, kvaL, xr, meta2, cls_start, ob, pxs, m0, w, l);
        __syncthreads();
        {
            f32x4 d = tileAb<4, 136>(&ob[0][0], Lb + PK_WO_A + w * 2048, l);
#pragma unroll
            for (int r = 0; r < 4; r++)
                zs[R4 + r][w * 16 + c0] = d[r] + hn[R4 + r][w * 16 + c0];
        }
        __syncthreads();
        ln_rows(zs, hL, &hb[0][0], ln1g + lay * DM, ln1b + lay * DM, w, l);
        __syncthreads();

        // P3: qkv_e -> kveL
        {
            f32x4 aq = tileAb<4, 136>(&hb[0][0], Lb + PK_QKV_E + 0 * 16384 + w * 2048, l);
#pragma unroll
            for (int r = 0; r < 4; r++) qsb[R4 + r][w * 16 + c0] = f2b(aq[r]);
            f32x4 ak = tileAb<4, 136>(&hb[0][0], Lb + PK_QKV_E + 1 * 16384 + w * 2048, l);
            f32x4 av = tileAb<4, 136>(&hb[0][0], Lb + PK_QKV_E + 2 * 16384 + w * 2048, l);
#pragma unroll
            for (int r = 0; r < 4; r++) {
                ub[R4 + r][w * 16 + c0] = f2b(ak[r]);
                ub[R4 + r][128 + w * 16 + c0] = f2b(av[r]);
            }
            __syncthreads();
            for (int u = tid; u < BR * 64; u += 512) {
                int r = u >> 6, rest = u & 63, hh = rest >> 3, j = rest & 7;
                int so = (j < 4) ? (hh * 16 + j * 4) : (128 + hh * 16 + (j - 4) * 4);
                u64 val = *reinterpret_cast<const u64*>(&ub[r][so]);
                ast64(kveL + ((size_t)hh * NE + m0 + r) * 8 + j, val);
            }
        }
        gbar(barcnt, GRID * (++ph));

        // P4: inter attn + Wo + LN2
        attn_inter(qsb, kveL, idx_e, cnt_e, ob, m0, w, l);
        __syncthreads();
        {
            f32x4 d = tileAb<4, 136>(&ob[0][0], Lb + PK_WO_E + w * 2048, l);
#pragma unroll
            for (int r = 0; r < 4; r++)
                zs[R4 + r][w * 16 + c0] = d[r] + hL[R4 + r][w * 16 + c0];
        }
        __syncthreads();
        ln_rows(zs, hL, &hb[0][0], ln2g + lay * DM, ln2b + lay * DM, w, l);
        __syncthreads();

        // P5: FFN1 -> ub
#pragma unroll
        for (int j = 0; j < 4; j++) {
            int nt = w * 4 + j;
            f32x4 acc = tileAb<4, 136>(&hb[0][0], Lb + PK_W1 + nt * 2048, l);
#pragma unroll
            for (int r = 0; r < 4; r++) {
                int col = nt * 16 + c0;
                float xvv = acc[r] + b1g[lay * FF + col];
                xvv = xvv / (1.f + __expf(-xvv));
                ub[R4 + r][col] = f2b(xvv);
            }
        }
        __syncthreads();
        // FFN2 -> zs
        {
            f32x4 acc = tileAb<16, 520>(&ub[0][0], Lb + PK_W2 + w * 8192, l);
#pragma unroll
            for (int r = 0; r < 4; r++)
                zs[R4 + r][w * 16 + c0] = acc[r] + b2g[lay * DM + w * 16 + c0]
                                        + hL[R4 + r][w * 16 + c0];
        }
        __syncthreads();
        // LN3 + gate + coord (wave w: rows 2w, 2w+1)
        {
            const float* g3 = ln3g + lay * DM;
            const float* b3 = ln3b + lay * DM;
            const float* Wcl = Wcg + lay * DM;
            float bc0 = bcg[lay];
#pragma unroll
            for (int rr = 0; rr < 2; rr++) {
                int r = 2 * w + rr, row = m0 + r;
                int orow = perm[row];
                float z0 = zs[r][l], z1 = zs[r][64 + l];
                float s = z0 + z1;
#pragma unroll
                for (int off = 32; off; off >>= 1) s += __shfl_xor(s, off);
                float mean = s * (1.f / DM);
                float d0 = z0 - mean, d1 = z1 - mean;
                float vsum = d0 * d0 + d1 * d1;
#pragma unroll
                for (int off = 32; off; off >>= 1) vsum += __shfl_xor(vsum, off);
                float inv = rsqrtf(vsum * (1.f / DM) + 1e-5f);
                float h0 = d0 * inv * g3[l] + b3[l];
                float h1 = d1 * inv * g3[64 + l] + b3[64 + l];
                hL[r][l] = h0; hL[r][64 + l] = h1;
                if (last) { outp[orow * DM + l] = h0; outp[orow * DM + 64 + l] = h1; }
                float dc = h0 * Wcl[l] + h1 * Wcl[64 + l];
#pragma unroll
                for (int off = 32; off; off >>= 1) dc += __shfl_xor(dc, off);
                float gate = tanhf(dc + bc0);
                if (l < 3) {
                    float pxm = 0.f;
#pragma unroll
                    for (int hh = 0; hh < NH; hh++) pxm += pxs[hh][r][l];
                    pxm *= 0.125f;
                    float xvv = xr[row * 4 + l];
                    float nx = xvv + gate * (xvv - pxm);
                    astf(xw2 + row * 4 + l, nx);
                    if (last) outp[NE * DM + orow * 3 + l] = nx;
                }
            }
        }
        __syncthreads();
    }
}

extern "C" void kernel_launch(void* const* d_in, const int* in_sizes, int n_in,
                              void* d_out, int out_size, void* d_ws, size_t ws_size,
                              hipStream_t stream) {
    const float* ef   = (const float*)d_in[0];
    const float* ec   = (const float*)d_in[1];
    const int*   eidx = (const int*)d_in[2];
    const float* nc   = (const float*)d_in[3];
    const int*   bids = (const int*)d_in[4];
    const float* b1   = (const float*)d_in[14];
    const float* b2   = (const float*)d_in[16];
    const float* ln1g = (const float*)d_in[17];
    const float* ln1b = (const float*)d_in[18];
    const float* ln2g = (const float*)d_in[19];
    const float* ln2b = (const float*)d_in[20];
    const float* ln3g = (const float*)d_in[21];
    const float* ln3b = (const float*)d_in[22];
    const float* Wc   = (const float*)d_in[24];
    const float* bc   = (const float*)d_in[25];
    float* out = (float*)d_out;

    char* w = (char*)d_ws;
    auto carve = [&](size_t bytes) { char* p = w; w += ((bytes + 255) / 256) * 256; return p; };
    int*   barcnt = (int*)carve(256);
    int*   hist   = (int*)carve(NCLS * 4);
    int*   csta   = (int*)carve((NCLS + 1) * 4);
    int*   fill   = (int*)carve(NCLS * 4);
    int*   key    = (int*)carve((size_t)NE * 4);
    int*   perm   = (int*)carve((size_t)NE * 4);
    int4*  metaO  = (int4*)carve((size_t)NE * 16);
    int4*  meta2  = (int4*)carve((size_t)NE * 16);
    float* xv     = (float*)carve((size_t)(NL + 1) * NE * 4 * 4);
    int*   cnt_e  = (int*)carve((size_t)NE * 4);
    u16*   idx_e  = (u16*)carve((size_t)NE * CAP * 2);
    float* rbf_g  = (float*)carve((size_t)NE * NR * 4);
    float* h_in   = (float*)carve((size_t)NE * DM * 4);
    short* kva    = (short*)carve((size_t)NL * NH * NE * 32 * 2);
    short* kve    = (short*)carve((size_t)NL * NH * NE * 32 * 2);
    short* pk     = (short*)carve((size_t)NL * PK_LAYER * 2);

    WSrc ws;
    ws.W[0] = (const float*)d_in[5];   ws.W[1] = (const float*)d_in[6];
    ws.W[2] = (const float*)d_in[7];   ws.W[3] = (const float*)d_in[8];
    ws.W[4] = (const float*)d_in[9];   ws.W[5] = (const float*)d_in[10];
    ws.W[6] = (const float*)d_in[11];  ws.W[7] = (const float*)d_in[12];
    ws.W[8] = (const float*)d_in[13];  ws.W[9] = (const float*)d_in[15];
    ws.W[10] = (const float*)d_in[23];
    pack_w<<<(NL * PK_LAYER + 255) / 256, 256, 0, stream>>>(ws, pk);

    zero_hist<<<1, 256, 0, stream>>>(hist, barcnt);
    k_meta<<<(NE + 255) / 256, 256, 0, stream>>>(eidx, bids, metaO, key, hist);
    k_scan<<<1, 256, 0, stream>>>(hist, csta, fill);
    k_scatter<<<(NE + 255) / 256, 256, 0, stream>>>(key, fill, perm);
    prep2<<<NE, 64, 0, stream>>>(ef, ec, nc, perm, metaO, meta2, h_in, xv, rbf_g);
    build_lists<<<NE, 64, 0, stream>>>(meta2, idx_e, cnt_e);

    mega_kernel<<<GRID, 512, 0, stream>>>(h_in, rbf_g, meta2, csta, perm,
                                          idx_e, cnt_e, pk,
                                          b1, b2, ln1g, ln1b, ln2g, ln2b, ln3g, ln3b,
                                          Wc, bc, kva, kve, xv, barcnt, out);
}